// Round 1
// baseline (2593.356 us; speedup 1.0000x reference)
//
#include <hip/hip_runtime.h>

#define N_NODES 100000
#define N_EDGES 3200000
#define NFEAT 512
#define NHID 256
#define NCLASS 64
#define KHOPS 10
#define SCAN_B 391   // ceil(N_NODES/256)

#define SW 16        // feature slice width
#define NSLICE 4     // NCLASS / SW

typedef __bf16 bf16x8 __attribute__((ext_vector_type(8)));
typedef __bf16 bf16x4 __attribute__((ext_vector_type(4)));
typedef float f32x4 __attribute__((ext_vector_type(4)));

// ---------------- preprocessing: degrees, dinv, CSR ----------------

__global__ __launch_bounds__(256) void zero_deg_kernel(int* __restrict__ deg) {
    int i = blockIdx.x * 256 + threadIdx.x;
    if (i < N_NODES) deg[i] = 0;
}

__global__ __launch_bounds__(256) void deg_kernel(const int* __restrict__ ei, int* __restrict__ deg) {
    int e = blockIdx.x * 256 + threadIdx.x;
    if (e < N_EDGES) atomicAdd(&deg[ei[N_EDGES + e]], 1);
}

__global__ __launch_bounds__(256) void dinv_kernel(const int* __restrict__ deg, float* __restrict__ dinv) {
    int i = blockIdx.x * 256 + threadIdx.x;
    if (i < N_NODES) dinv[i] = rsqrtf((float)(deg[i] + 1)); // +1 self-loop
}

// ---- hierarchical scan of (deg[i]+1): partial sums -> scan partials -> local scan ----

__global__ __launch_bounds__(256) void scan1_kernel(const int* __restrict__ deg, int* __restrict__ partial) {
    __shared__ int red[256];
    int t = threadIdx.x;
    int i = blockIdx.x * 256 + t;
    red[t] = (i < N_NODES) ? deg[i] + 1 : 0;
    __syncthreads();
    for (int off = 128; off > 0; off >>= 1) {
        if (t < off) red[t] += red[t + off];
        __syncthreads();
    }
    if (t == 0) partial[blockIdx.x] = red[0];
}

__global__ __launch_bounds__(512) void scan2_kernel(int* __restrict__ partial) {
    __shared__ int s[512];
    int t = threadIdx.x;
    int v = (t < SCAN_B) ? partial[t] : 0;
    s[t] = v;
    __syncthreads();
    for (int off = 1; off < 512; off <<= 1) {
        int add = (t >= off) ? s[t - off] : 0;
        __syncthreads();
        s[t] += add;
        __syncthreads();
    }
    if (t < SCAN_B) partial[t] = s[t] - v; // exclusive
}

__global__ __launch_bounds__(256) void scan3_kernel(const int* __restrict__ deg,
                                                    const int* __restrict__ partial,
                                                    int* __restrict__ row_ptr,
                                                    int* __restrict__ cursor) {
    __shared__ int s[256];
    int t = threadIdx.x;
    int i = blockIdx.x * 256 + t;
    int v = (i < N_NODES) ? deg[i] + 1 : 0;
    s[t] = v;
    __syncthreads();
    for (int off = 1; off < 256; off <<= 1) {
        int add = (t >= off) ? s[t - off] : 0;
        __syncthreads();
        s[t] += add;
        __syncthreads();
    }
    int excl = s[t] - v + partial[blockIdx.x];
    if (i < N_NODES) {
        row_ptr[i] = excl;
        cursor[i] = excl;
        if (i == N_NODES - 1) row_ptr[N_NODES] = excl + v;
    }
}

// edges store ONLY the source index (4B) — weights are folded into u-space:
// u = dinv .* h;  u'[d] = dinv[d]^2 * (sum_{s in N(d)} u[s] + u[d])
__global__ __launch_bounds__(256) void fill_kernel(const int* __restrict__ ei,
                                                   int* __restrict__ cursor,
                                                   int* __restrict__ esrc) {
    int e = blockIdx.x * 256 + threadIdx.x;
    if (e < N_EDGES) {
        int s = ei[e], d = ei[N_EDGES + e];
        int p = atomicAdd(&cursor[d], 1);
        esrc[p] = s;
    } else if (e < N_EDGES + N_NODES) {
        int i = e - N_EDGES;
        int p = atomicAdd(&cursor[i], 1);
        esrc[p] = i; // self-loop
    }
}

// ---------------- weight prep: W1^T, W2^T in bf16 ----------------

__global__ __launch_bounds__(256) void wprep_kernel(const float* __restrict__ W1,
                                                    const float* __restrict__ W2,
                                                    __bf16* __restrict__ w1t,
                                                    __bf16* __restrict__ w2t) {
    int i = blockIdx.x * 256 + threadIdx.x;
    if (i < NFEAT * NHID) {
        int n = i >> 9, k = i & 511;           // w1t[n][k], k<512
        w1t[i] = (__bf16)W1[k * NHID + n];
    } else {
        int j = i - NFEAT * NHID;
        if (j < NHID * NCLASS) {
            int n = j >> 8, k = j & 255;       // w2t[n][k], k<256
            w2t[j] = (__bf16)W2[k * NCLASS + n];
        }
    }
}

// ---------------- fused MLP via bf16 MFMA ----------------

#define MT 64
#define KC 64
#define XP 72
#define WP 72
#define HP 264

__global__ __launch_bounds__(256) void mlp_kernel(const float* __restrict__ x,
                                                  const __bf16* __restrict__ w1t,
                                                  const float* __restrict__ b1,
                                                  const __bf16* __restrict__ w2t,
                                                  const float* __restrict__ b2,
                                                  const float* __restrict__ temp,
                                                  const float* __restrict__ dinv,
                                                  __bf16* __restrict__ u0,      // [NSLICE][N][SW]
                                                  float* __restrict__ hidden) {
    __shared__ char smem[46080] __attribute__((aligned(16)));
    __bf16* xs  = (__bf16*)smem;             // 64*72*2  = 9216 B
    __bf16* wt  = (__bf16*)(smem + 9216);    // 256*72*2 = 36864 B
    __bf16* h1s = (__bf16*)smem;             // 64*264*2 = 33792 B (after barrier)

    int t = threadIdx.x;
    int wv = t >> 6, lane = t & 63;
    int lrow = lane & 15;
    int quad = lane >> 4;
    int row0 = blockIdx.x * MT;
    int n0 = wv * 64;

    f32x4 acc[4][4] = {};
    for (int kc = 0; kc < NFEAT; kc += KC) {
        __syncthreads();
        for (int i = t; i < MT * 16; i += 256) {
            int r = i >> 4, c4 = i & 15;
            int row = row0 + r; if (row >= N_NODES) row = N_NODES - 1;
            float4 v = *(const float4*)&x[(size_t)row * NFEAT + kc + c4 * 4];
            bf16x4 o = { (__bf16)v.x, (__bf16)v.y, (__bf16)v.z, (__bf16)v.w };
            *(bf16x4*)&xs[r * XP + c4 * 4] = o;
        }
        for (int i = t; i < 256 * 8; i += 256) {
            int n = i >> 3, c8 = i & 7;
            bf16x8 v = *(const bf16x8*)&w1t[(size_t)n * NFEAT + kc + c8 * 8];
            *(bf16x8*)&wt[n * WP + c8 * 8] = v;
        }
        __syncthreads();
        #pragma unroll
        for (int ks = 0; ks < 2; ++ks) {
            int kof = ks * 32 + quad * 8;
            bf16x8 a[4], b[4];
            #pragma unroll
            for (int mt = 0; mt < 4; ++mt)
                a[mt] = *(const bf16x8*)&xs[(mt * 16 + lrow) * XP + kof];
            #pragma unroll
            for (int nt = 0; nt < 4; ++nt)
                b[nt] = *(const bf16x8*)&wt[(n0 + nt * 16 + lrow) * WP + kof];
            #pragma unroll
            for (int mt = 0; mt < 4; ++mt)
                #pragma unroll
                for (int nt = 0; nt < 4; ++nt)
                    acc[mt][nt] = __builtin_amdgcn_mfma_f32_16x16x32_bf16(a[mt], b[nt], acc[mt][nt], 0, 0, 0);
        }
    }
    __syncthreads();
    #pragma unroll
    for (int nt = 0; nt < 4; ++nt) {
        int coln = n0 + nt * 16 + lrow;
        float bb = b1[coln];
        #pragma unroll
        for (int mt = 0; mt < 4; ++mt) {
            int rbase = mt * 16 + quad * 4;
            #pragma unroll
            for (int r = 0; r < 4; ++r) {
                float v = acc[mt][nt][r] + bb;
                h1s[(rbase + r) * HP + coln] = (__bf16)fmaxf(v, 0.f);
            }
        }
    }
    __syncthreads();
    f32x4 acc2[4] = {};
    #pragma unroll
    for (int ks = 0; ks < 8; ++ks) {
        int kof = ks * 32 + quad * 8;
        bf16x8 a2 = *(const bf16x8*)&h1s[(wv * 16 + lrow) * HP + kof];
        #pragma unroll
        for (int nt = 0; nt < 4; ++nt) {
            bf16x8 bv = *(const bf16x8*)&w2t[(size_t)(nt * 16 + lrow) * NHID + kof];
            acc2[nt] = __builtin_amdgcn_mfma_f32_16x16x32_bf16(a2, bv, acc2[nt], 0, 0, 0);
        }
    }
    float t0 = temp[0];
    #pragma unroll
    for (int nt = 0; nt < 4; ++nt) {
        int coln = nt * 16 + lrow;               // slice = nt, feat-in-slice = lrow
        float bb = b2[coln];
        #pragma unroll
        for (int r = 0; r < 4; ++r) {
            int row = row0 + wv * 16 + quad * 4 + r;
            if (row < N_NODES) {
                float v = acc2[nt][r] + bb;
                hidden[(size_t)row * NCLASS + coln] = t0 * v;
                u0[((size_t)nt * N_NODES + row) * SW + lrow] = (__bf16)(dinv[row] * v);
            }
        }
    }
}

// ---------------- propagation: L2-resident 16-feature slices ----------------
// gridDim = (N/4, NSLICE); x-fastest dispatch order keeps concurrent blocks on
// one 3.2MB slice -> gathers hit per-XCD L2 instead of L3 random access.
// wave per dst node; 32 edges/iter, 2 lanes/edge (16B each); butterfly over
// eslot bits (xor 2,4,8,16,32); lanes 0-1 scale by dinv^2, write u_out slice
// and fuse the hidden += temp[k]*dinv*sum update.

__global__ __launch_bounds__(256) void prop_kernel(const __bf16* __restrict__ uin,   // [NSLICE][N][SW]
                                                   __bf16* __restrict__ uout,
                                                   float* __restrict__ hidden,       // [N][64]
                                                   const int* __restrict__ row_ptr,
                                                   const int* __restrict__ esrc,
                                                   const float* __restrict__ dinv,
                                                   const float* __restrict__ temp,
                                                   int ktap) {
    int slice = blockIdx.y;
    int node = blockIdx.x * 4 + (threadIdx.x >> 6);
    int lane = threadIdx.x & 63;
    int eslot = lane >> 1, half = lane & 1;
    int beg = row_ptr[node], end = row_ptr[node + 1];
    const __bf16* ub = uin + (size_t)slice * N_NODES * SW;
    float acc[8] = {};
    int nit = (end - beg + 31) >> 5;
    for (int it = 0; it < nit; ++it) {
        int e = beg + it * 32 + eslot;
        int ec = min(e, end - 1);                      // clamped (self-loop => end>beg)
        int s = __builtin_nontemporal_load(&esrc[ec]); // streamed, keep L2 for uin
        float m = (e < end) ? 1.f : 0.f;
        uint4 v = *(const uint4*)(ub + (size_t)s * SW + half * 8);
        unsigned vv;
        vv = v.x;
        acc[0] = fmaf(m, __int_as_float(vv << 16), acc[0]);
        acc[1] = fmaf(m, __int_as_float(vv & 0xffff0000u), acc[1]);
        vv = v.y;
        acc[2] = fmaf(m, __int_as_float(vv << 16), acc[2]);
        acc[3] = fmaf(m, __int_as_float(vv & 0xffff0000u), acc[3]);
        vv = v.z;
        acc[4] = fmaf(m, __int_as_float(vv << 16), acc[4]);
        acc[5] = fmaf(m, __int_as_float(vv & 0xffff0000u), acc[5]);
        vv = v.w;
        acc[6] = fmaf(m, __int_as_float(vv << 16), acc[6]);
        acc[7] = fmaf(m, __int_as_float(vv & 0xffff0000u), acc[7]);
    }
    #pragma unroll
    for (int j = 0; j < 8; ++j) {
        acc[j] += __shfl_xor(acc[j], 2);
        acc[j] += __shfl_xor(acc[j], 4);
        acc[j] += __shfl_xor(acc[j], 8);
        acc[j] += __shfl_xor(acc[j], 16);
        acc[j] += __shfl_xor(acc[j], 32);
    }
    if (eslot == 0) { // lanes 0 (feats 0-7) and 1 (feats 8-15)
        float di = dinv[node];
        float d2 = di * di;
        float tk = temp[ktap] * di;
        union { __bf16 b[8]; uint4 u; } pk;
        #pragma unroll
        for (int j = 0; j < 8; ++j) pk.b[j] = (__bf16)(d2 * acc[j]);
        *(uint4*)(uout + ((size_t)slice * N_NODES + node) * SW + half * 8) = pk.u;
        float* hp = hidden + (size_t)node * NCLASS + slice * SW + half * 8;
        float4 a = *(float4*)hp, b = *(float4*)(hp + 4);
        a.x = fmaf(tk, acc[0], a.x); a.y = fmaf(tk, acc[1], a.y);
        a.z = fmaf(tk, acc[2], a.z); a.w = fmaf(tk, acc[3], a.w);
        b.x = fmaf(tk, acc[4], b.x); b.y = fmaf(tk, acc[5], b.y);
        b.z = fmaf(tk, acc[6], b.z); b.w = fmaf(tk, acc[7], b.w);
        *(float4*)hp = a; *(float4*)(hp + 4) = b;
    }
}

// ---------------- log_softmax in-place on d_out ----------------

__global__ __launch_bounds__(256) void lsm_kernel(float* __restrict__ io) {
    int i = blockIdx.x * 4 + (threadIdx.x >> 6);
    int j = threadIdx.x & 63;
    float v = io[(size_t)i * 64 + j];
    float m = v;
    #pragma unroll
    for (int o = 32; o > 0; o >>= 1) m = fmaxf(m, __shfl_xor(m, o));
    float ex = expf(v - m);
    float s = ex;
    #pragma unroll
    for (int o = 32; o > 0; o >>= 1) s += __shfl_xor(s, o);
    io[(size_t)i * 64 + j] = v - m - logf(s);
}

extern "C" void kernel_launch(void* const* d_in, const int* in_sizes, int n_in,
                              void* d_out, int out_size, void* d_ws, size_t ws_size,
                              hipStream_t stream) {
    const float* x    = (const float*)d_in[0];
    const int*   ei   = (const int*)d_in[1];
    const float* W1   = (const float*)d_in[2];
    const float* b1   = (const float*)d_in[3];
    const float* W2   = (const float*)d_in[4];
    const float* b2   = (const float*)d_in[5];
    const float* temp = (const float*)d_in[6];
    float* out = (float*)d_out;

    char* ws = (char*)d_ws;
    size_t off = 0;
    auto alloc = [&](size_t bytes) -> void* {
        void* p = ws + off;
        off = (off + bytes + 255) & ~(size_t)255;
        return p;
    };
    int*    deg     = (int*)alloc((size_t)N_NODES * 4);
    float*  dinv    = (float*)alloc((size_t)N_NODES * 4);
    int*    row_ptr = (int*)alloc((size_t)(N_NODES + 1) * 4);
    int*    cursor  = (int*)alloc((size_t)N_NODES * 4);
    int*    partial = (int*)alloc((size_t)SCAN_B * 4);
    int*    esrc    = (int*)alloc((size_t)(N_EDGES + N_NODES) * 4);
    __bf16* ub0     = (__bf16*)alloc((size_t)N_NODES * NCLASS * 2);
    __bf16* ub1     = (__bf16*)alloc((size_t)N_NODES * NCLASS * 2);
    __bf16* w1t     = (__bf16*)alloc((size_t)NFEAT * NHID * 2);
    __bf16* w2t     = (__bf16*)alloc((size_t)NHID * NCLASS * 2);

    zero_deg_kernel<<<(N_NODES + 255) / 256, 256, 0, stream>>>(deg);
    deg_kernel<<<(N_EDGES + 255) / 256, 256, 0, stream>>>(ei, deg);
    dinv_kernel<<<(N_NODES + 255) / 256, 256, 0, stream>>>(deg, dinv);
    scan1_kernel<<<SCAN_B, 256, 0, stream>>>(deg, partial);
    scan2_kernel<<<1, 512, 0, stream>>>(partial);
    scan3_kernel<<<SCAN_B, 256, 0, stream>>>(deg, partial, row_ptr, cursor);
    fill_kernel<<<(N_EDGES + N_NODES + 255) / 256, 256, 0, stream>>>(ei, cursor, esrc);
    wprep_kernel<<<(NFEAT * NHID + NHID * NCLASS + 255) / 256, 256, 0, stream>>>(W1, W2, w1t, w2t);

    mlp_kernel<<<(N_NODES + MT - 1) / MT, 256, 0, stream>>>(x, w1t, b1, w2t, b2, temp, dinv, ub0, out);

    __bf16* cur = ub0;
    __bf16* nxt = ub1;
    dim3 pgrid(N_NODES / 4, NSLICE);
    for (int k = 0; k < KHOPS; ++k) {
        prop_kernel<<<pgrid, 256, 0, stream>>>(cur, nxt, out, row_ptr, esrc, dinv, temp, k + 1);
        __bf16* tswap = cur; cur = nxt; nxt = tswap;
    }

    lsm_kernel<<<N_NODES / 4, 256, 0, stream>>>(out);
}

// Round 2
// 1237.761 us; speedup vs baseline: 2.0952x; 2.0952x over previous
//
#include <hip/hip_runtime.h>

#define N_NODES 100000
#define N_EDGES 3200000
#define NFEAT 512
#define NHID 256
#define NCLASS 64
#define KHOPS 10
#define SCAN_B 391   // ceil(N_NODES/256)

// radix-partition CSR build
#define NBSHIFT 9
#define NBUCK 196    // ceil(N_NODES/512)
#define BCAP 20480   // >= max bucket size (avg 16.3K, sigma ~128)
#define TILE 4096

typedef __bf16 bf16x8 __attribute__((ext_vector_type(8)));
typedef __bf16 bf16x4 __attribute__((ext_vector_type(4)));
typedef float f32x4 __attribute__((ext_vector_type(4)));

// ---------------- preprocessing: degrees, dinv, CSR ----------------

__global__ __launch_bounds__(256) void zero_deg_kernel(int* __restrict__ deg, int* __restrict__ bcursor) {
    int i = blockIdx.x * 256 + threadIdx.x;
    if (i < N_NODES) deg[i] = 0;
    if (blockIdx.x == 0 && threadIdx.x < NBUCK) bcursor[threadIdx.x] = 0;
}

__global__ __launch_bounds__(256) void deg_kernel(const int* __restrict__ ei, int* __restrict__ deg) {
    int e = blockIdx.x * 256 + threadIdx.x;
    if (e < N_EDGES) atomicAdd(&deg[ei[N_EDGES + e]], 1);
}

__global__ __launch_bounds__(256) void dinv_kernel(const int* __restrict__ deg, float* __restrict__ dinv) {
    int i = blockIdx.x * 256 + threadIdx.x;
    if (i < N_NODES) dinv[i] = rsqrtf((float)(deg[i] + 1)); // +1 self-loop
}

// ---- hierarchical scan of (deg[i]+1): partial sums -> scan partials -> local scan ----

__global__ __launch_bounds__(256) void scan1_kernel(const int* __restrict__ deg, int* __restrict__ partial) {
    __shared__ int red[256];
    int t = threadIdx.x;
    int i = blockIdx.x * 256 + t;
    red[t] = (i < N_NODES) ? deg[i] + 1 : 0;
    __syncthreads();
    for (int off = 128; off > 0; off >>= 1) {
        if (t < off) red[t] += red[t + off];
        __syncthreads();
    }
    if (t == 0) partial[blockIdx.x] = red[0];
}

__global__ __launch_bounds__(512) void scan2_kernel(int* __restrict__ partial) {
    __shared__ int s[512];
    int t = threadIdx.x;
    int v = (t < SCAN_B) ? partial[t] : 0;
    s[t] = v;
    __syncthreads();
    for (int off = 1; off < 512; off <<= 1) {
        int add = (t >= off) ? s[t - off] : 0;
        __syncthreads();
        s[t] += add;
        __syncthreads();
    }
    if (t < SCAN_B) partial[t] = s[t] - v; // exclusive
}

__global__ __launch_bounds__(256) void scan3_kernel(const int* __restrict__ deg,
                                                    const int* __restrict__ partial,
                                                    int* __restrict__ row_ptr,
                                                    int* __restrict__ cursor) {
    __shared__ int s[256];
    int t = threadIdx.x;
    int i = blockIdx.x * 256 + t;
    int v = (i < N_NODES) ? deg[i] + 1 : 0;
    s[t] = v;
    __syncthreads();
    for (int off = 1; off < 256; off <<= 1) {
        int add = (t >= off) ? s[t - off] : 0;
        __syncthreads();
        s[t] += add;
        __syncthreads();
    }
    int excl = s[t] - v + partial[blockIdx.x];
    if (i < N_NODES) {
        row_ptr[i] = excl;
        cursor[i] = excl;
        if (i == N_NODES - 1) row_ptr[N_NODES] = excl + v;
    }
}

// ---- radix pass 1: partition edges by dst>>9 with per-block contiguous runs ----
// LDS-staged tile; one global cursor bump per (block,bucket); writes land in
// ~contiguous runs -> writeback ~= data size (fixes 197MB partial-line thrash).

__global__ __launch_bounds__(256) void radix1_kernel(const int* __restrict__ ei,
                                                     int* __restrict__ bcursor,
                                                     int2* __restrict__ breg) {
    __shared__ int2 stage[TILE];
    __shared__ int hist[NBUCK];
    __shared__ int base[NBUCK];
    __shared__ int offs[NBUCK];
    int t = threadIdx.x;
    int e0 = blockIdx.x * TILE;
    int n = N_EDGES - e0; if (n > TILE) n = TILE;
    for (int i = t; i < NBUCK; i += 256) { hist[i] = 0; offs[i] = 0; }
    __syncthreads();
    for (int i = t; i < n; i += 256) {
        int s = ei[e0 + i];
        int d = ei[N_EDGES + e0 + i];
        stage[i] = make_int2(s, d);
        atomicAdd(&hist[d >> NBSHIFT], 1);
    }
    __syncthreads();
    for (int i = t; i < NBUCK; i += 256)
        if (hist[i]) base[i] = atomicAdd(&bcursor[i], hist[i]);
    __syncthreads();
    for (int i = t; i < n; i += 256) {
        int2 e = stage[i];
        int b = e.y >> NBSHIFT;
        int slot = base[b] + atomicAdd(&offs[b], 1);
        if (slot < BCAP) breg[(size_t)b * BCAP + slot] = e;
    }
}

// ---- radix pass 2: bucket -> final CSR via LDS cursors; self-loop at segment head ----
// scatter confined to the bucket's ~66KB CSR region: lines dirty densely in L2.

__global__ __launch_bounds__(256) void radix2_kernel(const int2* __restrict__ breg,
                                                     const int* __restrict__ bcursor,
                                                     const int* __restrict__ row_ptr,
                                                     int* __restrict__ esrc) {
    __shared__ int lcur[512];
    int b = blockIdx.x;
    int t = threadIdx.x;
    int d0 = b << NBSHIFT;
    int nn = N_NODES - d0; if (nn > 512) nn = 512;
    for (int j = t; j < nn; j += 256) {
        int rp = row_ptr[d0 + j];
        lcur[j] = rp + 1;
        esrc[rp] = d0 + j;        // self-loop
    }
    __syncthreads();
    int cnt = bcursor[b]; if (cnt > BCAP) cnt = BCAP;
    const int2* bp = breg + (size_t)b * BCAP;
    for (int i = t; i < cnt; i += 256) {
        int2 e = bp[i];
        int p = atomicAdd(&lcur[e.y - d0], 1);
        esrc[p] = e.x;
    }
}

// fallback CSR fill (used only if workspace too small for radix buffer)
__global__ __launch_bounds__(256) void fill_kernel(const int* __restrict__ ei,
                                                   int* __restrict__ cursor,
                                                   int* __restrict__ esrc) {
    int e = blockIdx.x * 256 + threadIdx.x;
    if (e < N_EDGES) {
        int s = ei[e], d = ei[N_EDGES + e];
        int p = atomicAdd(&cursor[d], 1);
        esrc[p] = s;
    } else if (e < N_EDGES + N_NODES) {
        int i = e - N_EDGES;
        int p = atomicAdd(&cursor[i], 1);
        esrc[p] = i; // self-loop
    }
}

// ---------------- weight prep: W1^T, W2^T in bf16 ----------------

__global__ __launch_bounds__(256) void wprep_kernel(const float* __restrict__ W1,
                                                    const float* __restrict__ W2,
                                                    __bf16* __restrict__ w1t,
                                                    __bf16* __restrict__ w2t) {
    int i = blockIdx.x * 256 + threadIdx.x;
    if (i < NFEAT * NHID) {
        int n = i >> 9, k = i & 511;           // w1t[n][k], k<512
        w1t[i] = (__bf16)W1[k * NHID + n];
    } else {
        int j = i - NFEAT * NHID;
        if (j < NHID * NCLASS) {
            int n = j >> 8, k = j & 255;       // w2t[n][k], k<256
            w2t[j] = (__bf16)W2[k * NCLASS + n];
        }
    }
}

// ---------------- fused MLP via bf16 MFMA ----------------

#define MT 64
#define KC 64
#define XP 72
#define WP 72
#define HP 264

__global__ __launch_bounds__(256) void mlp_kernel(const float* __restrict__ x,
                                                  const __bf16* __restrict__ w1t,
                                                  const float* __restrict__ b1,
                                                  const __bf16* __restrict__ w2t,
                                                  const float* __restrict__ b2,
                                                  const float* __restrict__ temp,
                                                  const float* __restrict__ dinv,
                                                  __bf16* __restrict__ u0,      // [N][64]
                                                  float* __restrict__ hidden) {
    __shared__ char smem[46080] __attribute__((aligned(16)));
    __bf16* xs  = (__bf16*)smem;             // 64*72*2  = 9216 B
    __bf16* wt  = (__bf16*)(smem + 9216);    // 256*72*2 = 36864 B
    __bf16* h1s = (__bf16*)smem;             // 64*264*2 = 33792 B (after barrier)

    int t = threadIdx.x;
    int wv = t >> 6, lane = t & 63;
    int lrow = lane & 15;
    int quad = lane >> 4;
    int row0 = blockIdx.x * MT;
    int n0 = wv * 64;

    f32x4 acc[4][4] = {};
    for (int kc = 0; kc < NFEAT; kc += KC) {
        __syncthreads();
        for (int i = t; i < MT * 16; i += 256) {
            int r = i >> 4, c4 = i & 15;
            int row = row0 + r; if (row >= N_NODES) row = N_NODES - 1;
            float4 v = *(const float4*)&x[(size_t)row * NFEAT + kc + c4 * 4];
            bf16x4 o = { (__bf16)v.x, (__bf16)v.y, (__bf16)v.z, (__bf16)v.w };
            *(bf16x4*)&xs[r * XP + c4 * 4] = o;
        }
        for (int i = t; i < 256 * 8; i += 256) {
            int n = i >> 3, c8 = i & 7;
            bf16x8 v = *(const bf16x8*)&w1t[(size_t)n * NFEAT + kc + c8 * 8];
            *(bf16x8*)&wt[n * WP + c8 * 8] = v;
        }
        __syncthreads();
        #pragma unroll
        for (int ks = 0; ks < 2; ++ks) {
            int kof = ks * 32 + quad * 8;
            bf16x8 a[4], b[4];
            #pragma unroll
            for (int mt = 0; mt < 4; ++mt)
                a[mt] = *(const bf16x8*)&xs[(mt * 16 + lrow) * XP + kof];
            #pragma unroll
            for (int nt = 0; nt < 4; ++nt)
                b[nt] = *(const bf16x8*)&wt[(n0 + nt * 16 + lrow) * WP + kof];
            #pragma unroll
            for (int mt = 0; mt < 4; ++mt)
                #pragma unroll
                for (int nt = 0; nt < 4; ++nt)
                    acc[mt][nt] = __builtin_amdgcn_mfma_f32_16x16x32_bf16(a[mt], b[nt], acc[mt][nt], 0, 0, 0);
        }
    }
    __syncthreads();
    #pragma unroll
    for (int nt = 0; nt < 4; ++nt) {
        int coln = n0 + nt * 16 + lrow;
        float bb = b1[coln];
        #pragma unroll
        for (int mt = 0; mt < 4; ++mt) {
            int rbase = mt * 16 + quad * 4;
            #pragma unroll
            for (int r = 0; r < 4; ++r) {
                float v = acc[mt][nt][r] + bb;
                h1s[(rbase + r) * HP + coln] = (__bf16)fmaxf(v, 0.f);
            }
        }
    }
    __syncthreads();
    f32x4 acc2[4] = {};
    #pragma unroll
    for (int ks = 0; ks < 8; ++ks) {
        int kof = ks * 32 + quad * 8;
        bf16x8 a2 = *(const bf16x8*)&h1s[(wv * 16 + lrow) * HP + kof];
        #pragma unroll
        for (int nt = 0; nt < 4; ++nt) {
            bf16x8 bv = *(const bf16x8*)&w2t[(size_t)(nt * 16 + lrow) * NHID + kof];
            acc2[nt] = __builtin_amdgcn_mfma_f32_16x16x32_bf16(a2, bv, acc2[nt], 0, 0, 0);
        }
    }
    float t0 = temp[0];
    #pragma unroll
    for (int nt = 0; nt < 4; ++nt) {
        int coln = nt * 16 + lrow;
        float bb = b2[coln];
        #pragma unroll
        for (int r = 0; r < 4; ++r) {
            int row = row0 + wv * 16 + quad * 4 + r;
            if (row < N_NODES) {
                float v = acc2[nt][r] + bb;
                size_t idx = (size_t)row * NCLASS + coln;
                hidden[idx] = t0 * v;
                u0[idx] = (__bf16)(dinv[row] * v);   // u-space: u = dinv .* h
            }
        }
    }
}

// ---------------- propagation: full 128B row gathers in u-space ----------------
// wave per dst node, 8 lanes/edge, dwordx4 gathers of u[src][0..63] (bf16);
// butterfly shfl_xor(8/16/32); lanes 0-7 apply dinv^2 scale, write u_out and
// fuse hidden += temp[k]*dinv*sum. Edges are a 4B src-index stream (nontemporal).

__global__ __launch_bounds__(256) void prop_kernel(const __bf16* __restrict__ uin,
                                                   __bf16* __restrict__ uout,
                                                   float* __restrict__ hidden,
                                                   const int* __restrict__ row_ptr,
                                                   const int* __restrict__ esrc,
                                                   const float* __restrict__ dinv,
                                                   const float* __restrict__ temp,
                                                   int ktap) {
    int node = blockIdx.x * 4 + (threadIdx.x >> 6);
    int lane = threadIdx.x & 63;
    int oct = lane >> 3, fi8 = lane & 7;
    int beg = row_ptr[node], end = row_ptr[node + 1];
    const uint4* urow = (const uint4*)uin; // node stride 8 uint4s (128B)
    float acc[8] = {};
    int nit = (end - beg + 7) >> 3;
    #pragma unroll 4
    for (int it = 0; it < nit; ++it) {
        int e = beg + it * 8 + oct;
        int ec = min(e, end - 1);       // clamp (self-loop => end>beg)
        int s = __builtin_nontemporal_load(&esrc[ec]);
        float m = (e < end) ? 1.f : 0.f;
        uint4 v = urow[(size_t)s * 8 + fi8];
        unsigned vv;
        vv = v.x;
        acc[0] = fmaf(m, __int_as_float(vv << 16), acc[0]);
        acc[1] = fmaf(m, __int_as_float(vv & 0xffff0000u), acc[1]);
        vv = v.y;
        acc[2] = fmaf(m, __int_as_float(vv << 16), acc[2]);
        acc[3] = fmaf(m, __int_as_float(vv & 0xffff0000u), acc[3]);
        vv = v.z;
        acc[4] = fmaf(m, __int_as_float(vv << 16), acc[4]);
        acc[5] = fmaf(m, __int_as_float(vv & 0xffff0000u), acc[5]);
        vv = v.w;
        acc[6] = fmaf(m, __int_as_float(vv << 16), acc[6]);
        acc[7] = fmaf(m, __int_as_float(vv & 0xffff0000u), acc[7]);
    }
    #pragma unroll
    for (int j = 0; j < 8; ++j) {
        acc[j] += __shfl_xor(acc[j], 8);
        acc[j] += __shfl_xor(acc[j], 16);
        acc[j] += __shfl_xor(acc[j], 32);
    }
    if (oct == 0) {
        float di = dinv[node];
        float d2 = di * di;
        float tk = temp[ktap] * di;
        union { __bf16 b[8]; uint4 u; } pk;
        #pragma unroll
        for (int j = 0; j < 8; ++j) pk.b[j] = (__bf16)(d2 * acc[j]);
        ((uint4*)uout)[(size_t)node * 8 + fi8] = pk.u;
        float* hp = hidden + (size_t)node * NCLASS + fi8 * 8;
        float4 a = *(float4*)hp, b = *(float4*)(hp + 4);
        a.x = fmaf(tk, acc[0], a.x); a.y = fmaf(tk, acc[1], a.y);
        a.z = fmaf(tk, acc[2], a.z); a.w = fmaf(tk, acc[3], a.w);
        b.x = fmaf(tk, acc[4], b.x); b.y = fmaf(tk, acc[5], b.y);
        b.z = fmaf(tk, acc[6], b.z); b.w = fmaf(tk, acc[7], b.w);
        *(float4*)hp = a; *(float4*)(hp + 4) = b;
    }
}

// ---------------- log_softmax in-place on d_out ----------------

__global__ __launch_bounds__(256) void lsm_kernel(float* __restrict__ io) {
    int i = blockIdx.x * 4 + (threadIdx.x >> 6);
    int j = threadIdx.x & 63;
    float v = io[(size_t)i * 64 + j];
    float m = v;
    #pragma unroll
    for (int o = 32; o > 0; o >>= 1) m = fmaxf(m, __shfl_xor(m, o));
    float ex = expf(v - m);
    float s = ex;
    #pragma unroll
    for (int o = 32; o > 0; o >>= 1) s += __shfl_xor(s, o);
    io[(size_t)i * 64 + j] = v - m - logf(s);
}

extern "C" void kernel_launch(void* const* d_in, const int* in_sizes, int n_in,
                              void* d_out, int out_size, void* d_ws, size_t ws_size,
                              hipStream_t stream) {
    const float* x    = (const float*)d_in[0];
    const int*   ei   = (const int*)d_in[1];
    const float* W1   = (const float*)d_in[2];
    const float* b1   = (const float*)d_in[3];
    const float* W2   = (const float*)d_in[4];
    const float* b2   = (const float*)d_in[5];
    const float* temp = (const float*)d_in[6];
    float* out = (float*)d_out;

    char* ws = (char*)d_ws;
    size_t off = 0;
    auto alloc = [&](size_t bytes) -> void* {
        void* p = ws + off;
        off = (off + bytes + 255) & ~(size_t)255;
        return p;
    };
    int*    deg     = (int*)alloc((size_t)N_NODES * 4);
    float*  dinv    = (float*)alloc((size_t)N_NODES * 4);
    int*    row_ptr = (int*)alloc((size_t)(N_NODES + 1) * 4);
    int*    cursor  = (int*)alloc((size_t)N_NODES * 4);
    int*    partial = (int*)alloc((size_t)SCAN_B * 4);
    int*    bcursor = (int*)alloc((size_t)NBUCK * 4);
    int*    esrc    = (int*)alloc((size_t)(N_EDGES + N_NODES) * 4);
    __bf16* ub0     = (__bf16*)alloc((size_t)N_NODES * NCLASS * 2);
    __bf16* ub1     = (__bf16*)alloc((size_t)N_NODES * NCLASS * 2);
    __bf16* w1t     = (__bf16*)alloc((size_t)NFEAT * NHID * 2);
    __bf16* w2t     = (__bf16*)alloc((size_t)NHID * NCLASS * 2);
    size_t breg_bytes = (size_t)NBUCK * BCAP * 8;
    bool use_radix = (off + breg_bytes <= ws_size);
    int2* breg = use_radix ? (int2*)alloc(breg_bytes) : (int2*)0;

    zero_deg_kernel<<<(N_NODES + 255) / 256, 256, 0, stream>>>(deg, bcursor);
    deg_kernel<<<(N_EDGES + 255) / 256, 256, 0, stream>>>(ei, deg);
    dinv_kernel<<<(N_NODES + 255) / 256, 256, 0, stream>>>(deg, dinv);
    scan1_kernel<<<SCAN_B, 256, 0, stream>>>(deg, partial);
    scan2_kernel<<<1, 512, 0, stream>>>(partial);
    scan3_kernel<<<SCAN_B, 256, 0, stream>>>(deg, partial, row_ptr, cursor);
    if (use_radix) {
        radix1_kernel<<<(N_EDGES + TILE - 1) / TILE, 256, 0, stream>>>(ei, bcursor, breg);
        radix2_kernel<<<NBUCK, 256, 0, stream>>>(breg, bcursor, row_ptr, esrc);
    } else {
        fill_kernel<<<(N_EDGES + N_NODES + 255) / 256, 256, 0, stream>>>(ei, cursor, esrc);
    }
    wprep_kernel<<<(NFEAT * NHID + NHID * NCLASS + 255) / 256, 256, 0, stream>>>(W1, W2, w1t, w2t);

    mlp_kernel<<<(N_NODES + MT - 1) / MT, 256, 0, stream>>>(x, w1t, b1, w2t, b2, temp, dinv, ub0, out);

    __bf16* cur = ub0;
    __bf16* nxt = ub1;
    for (int k = 0; k < KHOPS; ++k) {
        prop_kernel<<<N_NODES / 4, 256, 0, stream>>>(cur, nxt, out, row_ptr, esrc, dinv, temp, k + 1);
        __bf16* tswap = cur; cur = nxt; nxt = tswap;
    }

    lsm_kernel<<<N_NODES / 4, 256, 0, stream>>>(out);
}